// Round 2
// 1282.936 us; speedup vs baseline: 1.0083x; 1.0083x over previous
//
#include <hip/hip_runtime.h>

typedef unsigned short u16;
typedef unsigned int u32;

typedef __attribute__((ext_vector_type(8))) short bf16x8;
typedef __attribute__((ext_vector_type(4))) float f32x4;
typedef __attribute__((ext_vector_type(2))) float f32x2;

// ---------- helpers ----------
__device__ __forceinline__ float bf2f(u16 v) {
    union { u32 i; float f; } u; u.i = ((u32)v) << 16; return u.f;
}
__device__ __forceinline__ u16 f2bf(float f) {
    union { float f; u32 i; } u; u.f = f;
    u32 r = u.i + 0x7FFFu + ((u.i >> 16) & 1u);   // RNE
    return (u16)(r >> 16);
}
__device__ __forceinline__ u32 pack2(float lo, float hi) {
    return (u32)f2bf(lo) | ((u32)f2bf(hi) << 16);
}
__device__ __forceinline__ void unpack8(uint4 r, float* o) {
    o[0] = __uint_as_float(r.x << 16); o[1] = __uint_as_float(r.x & 0xffff0000u);
    o[2] = __uint_as_float(r.y << 16); o[3] = __uint_as_float(r.y & 0xffff0000u);
    o[4] = __uint_as_float(r.z << 16); o[5] = __uint_as_float(r.z & 0xffff0000u);
    o[6] = __uint_as_float(r.w << 16); o[7] = __uint_as_float(r.w & 0xffff0000u);
}
__device__ __forceinline__ f32x2 pk_fma(f32x2 a, f32x2 b, f32x2 c) {
#if __has_builtin(__builtin_elementwise_fma)
    return __builtin_elementwise_fma(a, b, c);
#else
    return a * b + c;
#endif
}
__device__ __forceinline__ void async16(const void* g, void* l) {
    __builtin_amdgcn_global_load_lds((const __attribute__((address_space(1))) void*)g,
                                     (__attribute__((address_space(3))) void*)l, 16, 0, 0);
}
// DPP butterfly adds (VALU-only, no LDS pipe)
template<int CTRL>
__device__ __forceinline__ float dpp_add(float x) {
    int y = __builtin_amdgcn_update_dpp(0, __float_as_int(x), CTRL, 0xf, 0xf, true);
    return x + __int_as_float(y);
}
__device__ __forceinline__ float row16_allreduce(float x) {
    x = dpp_add<0xB1>(x);    // xor 1
    x = dpp_add<0x4E>(x);    // xor 2
    x = dpp_add<0x141>(x);   // row_half_mirror
    x = dpp_add<0x140>(x);   // row_mirror
    return x;
}
__device__ __forceinline__ float row8_allreduce(float x) {
    x = dpp_add<0xB1>(x);    // xor 1
    x = dpp_add<0x4E>(x);    // xor 2
    x = dpp_add<0x141>(x);   // row_half_mirror (= xor 7 within 8)
    return x;
}

// ---------- fp32 -> bf16 convert (elementwise, 8/thread) ----------
__global__ __launch_bounds__(256) void f2b_kernel(const float* __restrict__ in,
                                                  u16* __restrict__ out)
{
    long i = ((long)blockIdx.x * 256 + threadIdx.x) * 8;
    float4 a = *(const float4*)&in[i], b = *(const float4*)&in[i + 4];
    uint4 o = make_uint4(pack2(a.x, a.y), pack2(a.z, a.w), pack2(b.x, b.y), pack2(b.z, b.w));
    *(uint4*)&out[i] = o;
}

// ---------- fp32 RxC -> bf16 CxR transpose ----------
__global__ __launch_bounds__(256) void transpose_f2b(const float* __restrict__ in,
                                                     u16* __restrict__ out, int R, int C)
{
    __shared__ float tile[32][33];
    const int r0 = blockIdx.y * 32, c0 = blockIdx.x * 32;
    const int tr = threadIdx.x >> 3;
    const int tc = (threadIdx.x & 7) * 4;
    float4 v = *(const float4*)&in[(long)(r0 + tr) * C + c0 + tc];
    tile[tr][tc] = v.x; tile[tr][tc + 1] = v.y; tile[tr][tc + 2] = v.z; tile[tr][tc + 3] = v.w;
    __syncthreads();
    uint2 o;
    o.x = pack2(tile[tc][tr], tile[tc + 1][tr]);
    o.y = pack2(tile[tc + 2][tr], tile[tc + 3][tr]);
    *(uint2*)&out[(long)(c0 + tr) * R + r0 + tc] = o;
}

// ---------- GEMM (m97-style): C(MxN) = A(MxK) * Bt(NxK)^T, bf16 in, fp32 acc ----------
// CF=1: C fp32; CF=0: C bf16; CF=2: split store (qkv -> Cp compacted 8192-wide, z -> Cp2)
template<int CF>
__global__ __launch_bounds__(256) void gemm_bt(const u16* __restrict__ A,
                                               const u16* __restrict__ Bt,
                                               void* __restrict__ Cp,
                                               void* __restrict__ Cp2,
                                               int M, int N, int K)
{
    __shared__ __align__(16) u16 As[128 * 32];
    __shared__ __align__(16) u16 Bs[128 * 32];

    const int tid = threadIdx.x;
    const int lane = tid & 63;
    const int wave = tid >> 6;
    const int wm = (wave >> 1) * 64;
    const int wn = (wave & 1) * 64;
    const int lanelo = lane & 15;
    const int quad = lane >> 4;
    const long m0 = (long)blockIdx.y * 128;
    const long n0 = (long)blockIdx.x * 128;

    f32x4 acc[4][4];
#pragma unroll
    for (int i = 0; i < 4; ++i)
#pragma unroll
        for (int j = 0; j < 4; ++j) acc[i][j] = (f32x4)0.0f;

    const u16* agp0 = A + (long)(m0 + wave * 16 + (lane >> 2)) * K + (lane & 3) * 8;
    const u16* agp1 = agp0 + 64 * (long)K;
    const u16* bgp0 = Bt + (long)(n0 + wave * 16 + (lane >> 2)) * K + (lane & 3) * 8;
    const u16* bgp1 = bgp0 + 64 * (long)K;
    u16* lA0 = &As[wave * 16 * 32];
    u16* lA1 = &As[(wave * 16 + 64) * 32];
    u16* lB0 = &Bs[wave * 16 * 32];
    u16* lB1 = &Bs[(wave * 16 + 64) * 32];

    for (int k0 = 0; k0 < K; k0 += 32) {
        __syncthreads();
        async16(agp0 + k0, lA0);
        async16(agp1 + k0, lA1);
        async16(bgp0 + k0, lB0);
        async16(bgp1 + k0, lB1);
        __syncthreads();

        bf16x8 af[4], bf[4];
#pragma unroll
        for (int mt = 0; mt < 4; ++mt)
            af[mt] = *(const bf16x8*)&As[(wm + mt * 16 + lanelo) * 32 + quad * 8];
#pragma unroll
        for (int nt = 0; nt < 4; ++nt)
            bf[nt] = *(const bf16x8*)&Bs[(wn + nt * 16 + lanelo) * 32 + quad * 8];
#pragma unroll
        for (int mt = 0; mt < 4; ++mt)
#pragma unroll
            for (int nt = 0; nt < 4; ++nt)
                acc[mt][nt] = __builtin_amdgcn_mfma_f32_16x16x32_bf16(af[mt], bf[nt], acc[mt][nt], 0, 0, 0);
    }

#pragma unroll
    for (int nt = 0; nt < 4; ++nt) {
        const long col = n0 + wn + nt * 16 + lanelo;
        int hkq = 0, rr = 0;
        if constexpr (CF == 2) { hkq = (int)col / 768; rr = (int)col - hkq * 768; }
#pragma unroll
        for (int mt = 0; mt < 4; ++mt)
#pragma unroll
            for (int r = 0; r < 4; ++r) {
                long row = m0 + wm + mt * 16 + quad * 4 + r;
                if constexpr (CF == 1)      ((float*)Cp)[row * N + col] = acc[mt][nt][r];
                else if constexpr (CF == 0) ((u16*)Cp)[row * N + col] = f2bf(acc[mt][nt][r]);
                else {
                    u16 vv = f2bf(acc[mt][nt][r]);
                    if (rr < 512) ((u16*)Cp )[row * 8192 + hkq * 512 + rr] = vv;
                    else          ((u16*)Cp2)[row * 4096 + hkq * 256 + (rr - 512)] = vv;
                }
            }
    }
}

// ---------- ba = hs @ w_ba (2048x64): stores eg = exp(g) directly, plus beta ----------
__global__ __launch_bounds__(256) void ba_kernel(const float* __restrict__ hs,
                                                 const float* __restrict__ wba,
                                                 const float* __restrict__ A_log,
                                                 const float* __restrict__ dt_bias,
                                                 float* __restrict__ gbuf,
                                                 float* __restrict__ bbuf)
{
    const int m = blockIdx.x * 4 + (threadIdx.x >> 6);
    const int n = threadIdx.x & 63;
    const float* hrow = &hs[(long)m * 2048];
    float acc = 0.f;
#pragma unroll 8
    for (int k = 0; k < 2048; ++k)
        acc += hrow[k] * wba[(long)k * 64 + n];
    const int hk4 = n >> 2, r = n & 3;
    if (r < 2) {
        bbuf[(long)m * 32 + hk4 * 2 + r] = 1.f / (1.f + expf(-acc));
    } else {
        const int hv = hk4 * 2 + (r - 2);
        float x = acc + dt_bias[hv];
        float sp = (x > 20.f) ? x : log1pf(expf(x));
        gbuf[(long)m * 32 + hv] = expf(-expf(A_log[hv]) * sp);   // eg = exp(g)
    }
}

// ---------- causal depthwise conv (K=4) + silu + per-head l2norm ----------
// reads compacted qkvb (8192 cols/row); writes q,k as f32 (scan-only consumers), v as bf16
__global__ __launch_bounds__(256) void conv_kernel(const u16* __restrict__ qkvb,
                                                   const float* __restrict__ cw,
                                                   float* __restrict__ qfb,
                                                   float* __restrict__ kfb,
                                                   u16* __restrict__ vbuf)
{
    const int bid = blockIdx.x;          // bs*4 + part
    const int bs = bid >> 2, part = bid & 3;
    const int c = part * 2048 + threadIdx.x * 8;   // mixed channel [q|k|v]
    int n;
    if (c < 2048)       n = (c >> 7) * 512 + (c & 127);
    else if (c < 4096) { int c2 = c - 2048; n = (c2 >> 7) * 512 + 128 + (c2 & 127); }
    else               { int c2 = c - 4096; n = (c2 >> 8) * 512 + 256 + (c2 & 255); }
    const int s = bs & 2047;
    const long base = (long)bs * 8192 + n;

    float x0[8], x1[8], x2[8], x3[8];
#pragma unroll
    for (int i = 0; i < 8; ++i) { x0[i] = 0.f; x1[i] = 0.f; x2[i] = 0.f; }
    { uint4 r = *(const uint4*)&qkvb[base]; unpack8(r, x3); }
    if (s >= 1) { uint4 r = *(const uint4*)&qkvb[base - 8192];     unpack8(r, x2); }
    if (s >= 2) { uint4 r = *(const uint4*)&qkvb[base - 2 * 8192]; unpack8(r, x1); }
    if (s >= 3) { uint4 r = *(const uint4*)&qkvb[base - 3 * 8192]; unpack8(r, x0); }

    float v[8]; float ss = 0.f;
#pragma unroll
    for (int i = 0; i < 8; ++i) {
        float4 w = *(const float4*)&cw[(c + i) * 4];
        float a = x0[i] * w.x + x1[i] * w.y + x2[i] * w.z + x3[i] * w.w;
        v[i] = a / (1.f + expf(-a));
        ss += v[i] * v[i];
    }
    if (part < 2) {   // q/k: l2norm over 128-ch head = 16 consecutive lanes; f32 out
        ss = row16_allreduce(ss);
        float rn = rsqrtf(ss + 1e-6f);
#pragma unroll
        for (int i = 0; i < 8; ++i) v[i] *= rn;
        float* dst = (part == 0 ? qfb : kfb) + (long)bs * 2048 + (c & 2047);
        *(float4*)&dst[0] = make_float4(v[0], v[1], v[2], v[3]);
        *(float4*)&dst[4] = make_float4(v[4], v[5], v[6], v[7]);
    } else {          // v: bf16 out
        uint4 o = make_uint4(pack2(v[0], v[1]), pack2(v[2], v[3]), pack2(v[4], v[5]), pack2(v[6], v[7]));
        *(uint4*)&vbuf[(long)bs * 4096 + (c - 4096)] = o;
    }
}

// ---------- sequential gated delta scan, lookahead-linearized ----------
// Identity (exact):  k_t.S_{t-1} = eg_{t-1}*(k_t.S_{t-2}) + (k_t.k_{t-1})*delta_{t-1}
// =>  delta_t = be*v_t - (be*eg_t*eg_{t-1})*y_t - (be*eg_t*c_t)*delta_{t-1}
// y_t = k_t.S_{t-2} is reduced 2 steps early (off critical path); c_t = k_t.k_{t-1}
// precomputed per tile. Critical chain per step = ONE scalar fma.
// grid 512 = (b, h, col-block of 16); 256 thr; rg=lane&15 owns 8 rows; cloc = column.
__global__ __launch_bounds__(256) void scan_kernel(const float* __restrict__ kfb,
                                                   const float* __restrict__ qfb,
                                                   const u16* __restrict__ vbuf,
                                                   const float* __restrict__ gbuf,
                                                   const float* __restrict__ bbuf,
                                                   u16* __restrict__ obuf)
{
    // LDS row layout for k/q (swizzled for 2-way-free b128 reads):
    // row r, chunk j (16B): j<16 -> elems j*8..j*8+3 ; j>=16 -> elems (j-16)*8+4..+7
    __shared__ __align__(16) float lq[32 * 128];    // rows t0 .. t0+31
    __shared__ __align__(16) float lk[36 * 128];    // rows t0-1 .. t0+34 (clamped)
    __shared__ __align__(16) u16   lv[32 * 16];
    __shared__ __align__(16) float leg[34 * 4];     // eg rows t0-1 .. t0+31 (16B chunks)
    __shared__ __align__(16) float lbe[32 * 4];     // beta rows t0 .. t0+31
    __shared__ __align__(16) float lsc[32 * 4];     // per-step coeffs {be, -be*eg*eg', -be*eg*c, eg}

    const int bid = blockIdx.x;
    const int b = bid >> 8;
    const int h = (bid >> 3) & 31;
    const int c0 = (bid & 7) * 16;
    const int hk = h >> 1;
    const int tid = threadIdx.x;
    const int lane = tid & 63;
    const int rg = lane & 15;
    const int cloc = (tid >> 6) * 4 + (lane >> 4);   // 0..15
    const long rowbase = (long)b * 2048;
    const int h4 = h & ~3;
    const int hm = h & 3;
    const float scale = 0.08838834764831845f;  // 128^-0.5

    f32x2 S2[4];
#pragma unroll
    for (int i = 0; i < 4; ++i) S2[i] = (f32x2){0.f, 0.f};
    f32x2 kpipe[2][4];
#pragma unroll
    for (int i = 0; i < 4; ++i) { kpipe[0][i] = (f32x2){0.f, 0.f}; kpipe[1][i] = (f32x2){0.f, 0.f}; }
    float ypipe[2] = {0.f, 0.f};
    float dprev = 0.f;

    for (int t0 = 0; t0 < 2048; t0 += 32) {
        __syncthreads();
        // ---- stage k/q/v chunks via global->LDS (wave-aligned branches only)
        for (int rnd = 0; rnd < 9; ++rnd) {
            const int u = rnd * 256 + tid;
            if (u < 1152) {
                const int row = u >> 5, j = u & 31;
                int tg = t0 - 1 + row; tg = tg < 0 ? 0 : (tg > 2047 ? 2047 : tg);
                const int col = ((j & 15) << 3) + ((j >> 4) << 2);
                async16(&kfb[(rowbase + tg) * 2048 + hk * 128 + col], &lk[u * 4]);
            } else if (u < 2176) {
                const int u2 = u - 1152, row = u2 >> 5, j = u2 & 31;
                const int col = ((j & 15) << 3) + ((j >> 4) << 2);
                async16(&qfb[(rowbase + t0 + row) * 2048 + hk * 128 + col], &lq[u2 * 4]);
            } else if (u < 2240) {
                const int u3 = u - 2176, row = u3 >> 1, ch2 = u3 & 1;
                async16(&vbuf[(rowbase + t0 + row) * 4096 + h * 128 + c0 + ch2 * 8], &lv[u3 * 8]);
            }
        }
        // ---- small per-step scalars: plain vector load -> LDS store (65 lanes)
        if (tid < 65) {
            if (tid < 33) {
                int tg = t0 - 1 + tid; if (tg < 0) tg = 0;
                *(f32x4*)&leg[tid * 4] = *(const f32x4*)&gbuf[(rowbase + tg) * 32 + h4];
            } else {
                const int i = tid - 33;
                *(f32x4*)&lbe[i * 4] = *(const f32x4*)&bbuf[(rowbase + t0 + i) * 32 + h4];
            }
        }
        __syncthreads();   // drains vmcnt+lgkmcnt -> LDS ready

        // ---- per-step coeffs: c_t = k_t.k_{t-1} (8 lanes per step), then fuse with eg/be
        {
            const int tt = tid >> 3, d = tid & 7;
            const int r1 = tt + 1, r0 = tt;   // lk rows: global t0+tt and t0+tt-1
            f32x4 a0 = *(const f32x4*)&lk[r1 * 128 + (2 * d) * 4];
            f32x4 a1 = *(const f32x4*)&lk[r1 * 128 + 64 + (2 * d) * 4];
            f32x4 a2 = *(const f32x4*)&lk[r1 * 128 + (2 * d + 1) * 4];
            f32x4 a3 = *(const f32x4*)&lk[r1 * 128 + 64 + (2 * d + 1) * 4];
            f32x4 b0 = *(const f32x4*)&lk[r0 * 128 + (2 * d) * 4];
            f32x4 b1 = *(const f32x4*)&lk[r0 * 128 + 64 + (2 * d) * 4];
            f32x4 b2 = *(const f32x4*)&lk[r0 * 128 + (2 * d + 1) * 4];
            f32x4 b3 = *(const f32x4*)&lk[r0 * 128 + 64 + (2 * d + 1) * 4];
            f32x4 p = a0 * b0 + a1 * b1 + a2 * b2 + a3 * b3;
            float cpart = (p.x + p.y) + (p.z + p.w);
            cpart = row8_allreduce(cpart);
            if (d == 0) {
                const float eg  = leg[(tt + 1) * 4 + hm];
                const float egp = leg[tt * 4 + hm];
                const float be  = lbe[tt * 4 + hm];
                const float bege = be * eg;
                f32x4 sc;
                sc.x = be;
                sc.y = -bege * egp;
                sc.z = -bege * cpart;
                sc.w = eg;
                *(f32x4*)&lsc[tt * 4] = sc;
            }
        }
        __syncthreads();

        if (t0 == 0) {   // pipeline warm-up: k_0, k_1 live in lk rows 1,2; y=0 (S=0)
            f32x4 a = *(const f32x4*)&lk[1 * 128 + rg * 4];
            f32x4 c = *(const f32x4*)&lk[1 * 128 + 64 + rg * 4];
            kpipe[0][0] = (f32x2){a.x, a.y}; kpipe[0][1] = (f32x2){a.z, a.w};
            kpipe[0][2] = (f32x2){c.x, c.y}; kpipe[0][3] = (f32x2){c.z, c.w};
            a = *(const f32x4*)&lk[2 * 128 + rg * 4];
            c = *(const f32x4*)&lk[2 * 128 + 64 + rg * 4];
            kpipe[1][0] = (f32x2){a.x, a.y}; kpipe[1][1] = (f32x2){a.z, a.w};
            kpipe[1][2] = (f32x2){c.x, c.y}; kpipe[1][3] = (f32x2){c.z, c.w};
            ypipe[0] = 0.f; ypipe[1] = 0.f; dprev = 0.f;
        }

#pragma unroll
        for (int t = 0; t < 32; ++t) {
            const int cur = t & 1;
            // delta (critical chain = this one fma on dprev)
            const f32x4 sc = *(const f32x4*)&lsc[t * 4];
            const float vv = bf2f(lv[t * 16 + cloc]);
            const float Aa = fmaf(sc.y, ypipe[cur], sc.x * vv);
            const float dlt = fmaf(sc.z, dprev, Aa);
            dprev = dlt;
            // S_t = eg*S_{t-1} + k_t * dlt      (k_t staged in kpipe 2 steps ago)
            const f32x2 eg2 = (f32x2){sc.w, sc.w};
            const f32x2 dl2 = (f32x2){dlt, dlt};
#pragma unroll
            for (int j = 0; j < 4; ++j)
                S2[j] = pk_fma(S2[j], eg2, kpipe[cur][j] * dl2);
            // y_{t+2} = k_{t+2}.S_t  (reduce has 2 steps of slack)
            {
                f32x4 ka = *(const f32x4*)&lk[(t + 3) * 128 + rg * 4];
                f32x4 kb = *(const f32x4*)&lk[(t + 3) * 128 + 64 + rg * 4];
                f32x2 k0 = (f32x2){ka.x, ka.y}, k1 = (f32x2){ka.z, ka.w};
                f32x2 k2 = (f32x2){kb.x, kb.y}, k3 = (f32x2){kb.z, kb.w};
                f32x2 pa = k0 * S2[0];
                f32x2 pb = k1 * S2[1];
                pa = pk_fma(k2, S2[2], pa);
                pb = pk_fma(k3, S2[3], pb);
                pa = pa + pb;
                ypipe[cur] = row16_allreduce(pa.x + pa.y);
                kpipe[cur][0] = k0; kpipe[cur][1] = k1; kpipe[cur][2] = k2; kpipe[cur][3] = k3;
            }
            // o_t = scale * q_t.S_t  (store-only, latency-tolerant)
            {
                f32x4 qa = *(const f32x4*)&lq[t * 128 + rg * 4];
                f32x4 qb = *(const f32x4*)&lq[t * 128 + 64 + rg * 4];
                f32x2 oa = ((f32x2){qa.x, qa.y}) * S2[0];
                f32x2 ob = ((f32x2){qa.z, qa.w}) * S2[1];
                oa = pk_fma((f32x2){qb.x, qb.y}, S2[2], oa);
                ob = pk_fma((f32x2){qb.z, qb.w}, S2[3], ob);
                oa = oa + ob;
                const float oo = row16_allreduce(oa.x + oa.y);
                if (rg == 0)
                    obuf[((rowbase + t0 + t) * 32 + h) * 128 + c0 + cloc] = f2bf(oo * scale);
            }
        }
    }
}

// ---------- RMS-norm + gating: y = o*rsqrt(mean(o^2)+eps) * norm_w * silu(z) ----------
__global__ __launch_bounds__(128) void gate_kernel(const u16* __restrict__ obuf,
                                                   const u16* __restrict__ zbuf,
                                                   const float* __restrict__ norm_w,
                                                   u16* __restrict__ ybuf)
{
    const int bid = blockIdx.x;          // bs*32 + hv
    const int bs = bid >> 5, hv = bid & 31;
    const int dv = threadIdx.x;
    __shared__ float red[2];
    float v = bf2f(obuf[(long)bid * 128 + dv]);
    float ss = v * v;
    ss += __shfl_xor(ss, 1);  ss += __shfl_xor(ss, 2);  ss += __shfl_xor(ss, 4);
    ss += __shfl_xor(ss, 8);  ss += __shfl_xor(ss, 16); ss += __shfl_xor(ss, 32);
    if ((dv & 63) == 0) red[dv >> 6] = ss;
    __syncthreads();
    const float mean = (red[0] + red[1]) * (1.f / 128.f);
    const float rstd = rsqrtf(mean + 1e-6f);
    const int hk = hv >> 1;
    const float z = bf2f(zbuf[(long)bs * 4096 + hk * 256 + (hv & 1) * 128 + dv]);
    const float y = v * rstd * norm_w[dv] * (z / (1.f + expf(-z)));
    ybuf[(long)bs * 4096 + hv * 128 + dv] = f2bf(y);
}

// ---------- launch ----------
extern "C" void kernel_launch(void* const* d_in, const int* in_sizes, int n_in,
                              void* d_out, int out_size, void* d_ws, size_t ws_size,
                              hipStream_t stream)
{
    const float* hs      = (const float*)d_in[0];
    const float* w_qkvz  = (const float*)d_in[1];
    const float* w_ba    = (const float*)d_in[2];
    const float* conv_w  = (const float*)d_in[3];
    const float* A_log   = (const float*)d_in[4];
    const float* dt_bias = (const float*)d_in[5];
    const float* norm_w  = (const float*)d_in[6];
    const float* w_out   = (const float*)d_in[7];

    char* ws = (char*)d_ws;
    // footprint identical to previous version: 202,375,168 B
    u16*   qkvb   = (u16*)ws;                        //  67,108,864  [GEMM1 -> conv]
    float* kfb    = (float*)(ws + 67108864);         //  33,554,432  [conv -> scan]
    float* qfb    = (float*)(ws + 100663296);        //  33,554,432  [conv -> scan]
    u16*   vbuf   = (u16*)(ws + 134217728);          //  33,554,432  [conv -> scan]
    u16*   zbuf   = (u16*)(ws + 167772160);          //  33,554,432  [GEMM1 -> gate]
    float* gbuf   = (float*)(ws + 201326592);        //     524,288  [ba -> scan]
    float* bbuf   = (float*)(ws + 201850880);        //     524,288  (end 202,375,168)
    // aliases (lifetime-disjoint):
    u16*   hs_b    = (u16*)(ws + 67108864);          // 16.8MB, dead after GEMM1 (= kfb slot)
    u16*   wqkvz_t = (u16*)(ws + 100663296);         // 50.3MB, dead after GEMM1 (= qfb+vbuf slot)
    u16*   obuf    = (u16*)ws;                       // 33.6MB, scan out (= qkvb lo half, dead after conv)
    u16*   wout_t  = (u16*)(ws + 33554432);          // 16.8MB (= qkvb hi half, dead after conv)
    u16*   ybuf    = (u16*)(ws + 67108864);          // 33.6MB gate out (= kfb slot, dead after scan)

    // 1) dtype prep
    f2b_kernel<<<4096, 256, 0, stream>>>(hs, hs_b);
    transpose_f2b<<<dim3(384, 64), 256, 0, stream>>>(w_qkvz, wqkvz_t, 2048, 12288);
    // 2) qkvz = hs @ w_qkvz, split store: qkv compacted -> qkvb, z -> zbuf
    gemm_bt<2><<<dim3(96, 32), 256, 0, stream>>>(hs_b, wqkvz_t, qkvb, zbuf, 4096, 12288, 2048);
    // 3) eg/beta
    ba_kernel<<<1024, 256, 0, stream>>>(hs, w_ba, A_log, dt_bias, gbuf, bbuf);
    // 4) conv + silu + l2norm: q,k f32; v bf16 (overwrites hs_b / wqkvz_t regions)
    conv_kernel<<<4096 * 4, 256, 0, stream>>>(qkvb, conv_w, qfb, kfb, vbuf);
    // 5) gated delta scan (writes obuf over dead qkvb)
    scan_kernel<<<512, 256, 0, stream>>>(kfb, qfb, vbuf, gbuf, bbuf, obuf);
    // 6) w_out^T into dead qkvb hi half
    transpose_f2b<<<dim3(64, 128), 256, 0, stream>>>(w_out, wout_t, 4096, 2048);
    // 7) gating (writes ybuf over dead kfb)
    gate_kernel<<<4096 * 32, 128, 0, stream>>>(obuf, zbuf, norm_w, ybuf);
    // 8) out = y @ w_out (4096 x 2048 x 4096), fp32 out
    gemm_bt<1><<<dim3(16, 32), 256, 0, stream>>>(ybuf, wout_t, d_out, nullptr, 4096, 2048, 4096);
}

// Round 4
// 1032.671 us; speedup vs baseline: 1.2527x; 1.2423x over previous
//
#include <hip/hip_runtime.h>

typedef unsigned short u16;
typedef unsigned int u32;

typedef __attribute__((ext_vector_type(8))) short bf16x8;
typedef __attribute__((ext_vector_type(4))) float f32x4;
typedef __attribute__((ext_vector_type(2))) float f32x2;

// ---------- helpers ----------
__device__ __forceinline__ float bf2f(u16 v) {
    union { u32 i; float f; } u; u.i = ((u32)v) << 16; return u.f;
}
__device__ __forceinline__ u16 f2bf(float f) {
    union { float f; u32 i; } u; u.f = f;
    u32 r = u.i + 0x7FFFu + ((u.i >> 16) & 1u);   // RNE
    return (u16)(r >> 16);
}
__device__ __forceinline__ u32 pack2(float lo, float hi) {
    return (u32)f2bf(lo) | ((u32)f2bf(hi) << 16);
}
__device__ __forceinline__ void unpack8(uint4 r, float* o) {
    o[0] = __uint_as_float(r.x << 16); o[1] = __uint_as_float(r.x & 0xffff0000u);
    o[2] = __uint_as_float(r.y << 16); o[3] = __uint_as_float(r.y & 0xffff0000u);
    o[4] = __uint_as_float(r.z << 16); o[5] = __uint_as_float(r.z & 0xffff0000u);
    o[6] = __uint_as_float(r.w << 16); o[7] = __uint_as_float(r.w & 0xffff0000u);
}
__device__ __forceinline__ void async16(const void* g, void* l) {
    __builtin_amdgcn_global_load_lds((const __attribute__((address_space(1))) void*)g,
                                     (__attribute__((address_space(3))) void*)l, 16, 0, 0);
}
// DPP butterfly adds (used by conv)
template<int CTRL>
__device__ __forceinline__ float dpp_add(float x) {
    int y = __builtin_amdgcn_update_dpp(0, __float_as_int(x), CTRL, 0xf, 0xf, true);
    return x + __int_as_float(y);
}
__device__ __forceinline__ float row16_allreduce(float x) {
    x = dpp_add<0xB1>(x);
    x = dpp_add<0x4E>(x);
    x = dpp_add<0x141>(x);
    x = dpp_add<0x140>(x);
    return x;
}

// ---------- fp32 -> bf16 convert ----------
__global__ __launch_bounds__(256) void f2b_kernel(const float* __restrict__ in,
                                                  u16* __restrict__ out)
{
    long i = ((long)blockIdx.x * 256 + threadIdx.x) * 8;
    float4 a = *(const float4*)&in[i], b = *(const float4*)&in[i + 4];
    uint4 o = make_uint4(pack2(a.x, a.y), pack2(a.z, a.w), pack2(b.x, b.y), pack2(b.z, b.w));
    *(uint4*)&out[i] = o;
}

// ---------- fp32 RxC -> bf16 CxR transpose ----------
__global__ __launch_bounds__(256) void transpose_f2b(const float* __restrict__ in,
                                                     u16* __restrict__ out, int R, int C)
{
    __shared__ float tile[32][33];
    const int r0 = blockIdx.y * 32, c0 = blockIdx.x * 32;
    const int tr = threadIdx.x >> 3;
    const int tc = (threadIdx.x & 7) * 4;
    float4 v = *(const float4*)&in[(long)(r0 + tr) * C + c0 + tc];
    tile[tr][tc] = v.x; tile[tr][tc + 1] = v.y; tile[tr][tc + 2] = v.z; tile[tr][tc + 3] = v.w;
    __syncthreads();
    uint2 o;
    o.x = pack2(tile[tc][tr], tile[tc + 1][tr]);
    o.y = pack2(tile[tc + 2][tr], tile[tc + 3][tr]);
    *(uint2*)&out[(long)(c0 + tr) * R + r0 + tc] = o;
}

// ---------- GEMM (m97-style) ----------
// CF=1: C fp32; CF=0: C bf16; CF=2: split store (qkv -> Cp compacted 8192-wide, z -> Cp2)
template<int CF>
__global__ __launch_bounds__(256) void gemm_bt(const u16* __restrict__ A,
                                               const u16* __restrict__ Bt,
                                               void* __restrict__ Cp,
                                               void* __restrict__ Cp2,
                                               int M, int N, int K)
{
    __shared__ __align__(16) u16 As[128 * 32];
    __shared__ __align__(16) u16 Bs[128 * 32];

    const int tid = threadIdx.x;
    const int lane = tid & 63;
    const int wave = tid >> 6;
    const int wm = (wave >> 1) * 64;
    const int wn = (wave & 1) * 64;
    const int lanelo = lane & 15;
    const int quad = lane >> 4;
    const long m0 = (long)blockIdx.y * 128;
    const long n0 = (long)blockIdx.x * 128;

    f32x4 acc[4][4];
#pragma unroll
    for (int i = 0; i < 4; ++i)
#pragma unroll
        for (int j = 0; j < 4; ++j) acc[i][j] = (f32x4)0.0f;

    const u16* agp0 = A + (long)(m0 + wave * 16 + (lane >> 2)) * K + (lane & 3) * 8;
    const u16* agp1 = agp0 + 64 * (long)K;
    const u16* bgp0 = Bt + (long)(n0 + wave * 16 + (lane >> 2)) * K + (lane & 3) * 8;
    const u16* bgp1 = bgp0 + 64 * (long)K;
    u16* lA0 = &As[wave * 16 * 32];
    u16* lA1 = &As[(wave * 16 + 64) * 32];
    u16* lB0 = &Bs[wave * 16 * 32];
    u16* lB1 = &Bs[(wave * 16 + 64) * 32];

    for (int k0 = 0; k0 < K; k0 += 32) {
        __syncthreads();
        async16(agp0 + k0, lA0);
        async16(agp1 + k0, lA1);
        async16(bgp0 + k0, lB0);
        async16(bgp1 + k0, lB1);
        __syncthreads();

        bf16x8 af[4], bf[4];
#pragma unroll
        for (int mt = 0; mt < 4; ++mt)
            af[mt] = *(const bf16x8*)&As[(wm + mt * 16 + lanelo) * 32 + quad * 8];
#pragma unroll
        for (int nt = 0; nt < 4; ++nt)
            bf[nt] = *(const bf16x8*)&Bs[(wn + nt * 16 + lanelo) * 32 + quad * 8];
#pragma unroll
        for (int mt = 0; mt < 4; ++mt)
#pragma unroll
            for (int nt = 0; nt < 4; ++nt)
                acc[mt][nt] = __builtin_amdgcn_mfma_f32_16x16x32_bf16(af[mt], bf[nt], acc[mt][nt], 0, 0, 0);
    }

#pragma unroll
    for (int nt = 0; nt < 4; ++nt) {
        const long col = n0 + wn + nt * 16 + lanelo;
        int hkq = 0, rr = 0;
        if constexpr (CF == 2) { hkq = (int)col / 768; rr = (int)col - hkq * 768; }
#pragma unroll
        for (int mt = 0; mt < 4; ++mt)
#pragma unroll
            for (int r = 0; r < 4; ++r) {
                long row = m0 + wm + mt * 16 + quad * 4 + r;
                if constexpr (CF == 1)      ((float*)Cp)[row * N + col] = acc[mt][nt][r];
                else if constexpr (CF == 0) ((u16*)Cp)[row * N + col] = f2bf(acc[mt][nt][r]);
                else {
                    u16 vv = f2bf(acc[mt][nt][r]);
                    if (rr < 512) ((u16*)Cp )[row * 8192 + hkq * 512 + rr] = vv;
                    else          ((u16*)Cp2)[row * 4096 + hkq * 256 + (rr - 512)] = vv;
                }
            }
    }
}

// ---------- ba = hs @ w_ba: stores RAW g (log-decay) and beta ----------
__global__ __launch_bounds__(256) void ba_kernel(const float* __restrict__ hs,
                                                 const float* __restrict__ wba,
                                                 const float* __restrict__ A_log,
                                                 const float* __restrict__ dt_bias,
                                                 float* __restrict__ gbuf,
                                                 float* __restrict__ bbuf)
{
    const int m = blockIdx.x * 4 + (threadIdx.x >> 6);
    const int n = threadIdx.x & 63;
    const float* hrow = &hs[(long)m * 2048];
    float acc = 0.f;
#pragma unroll 8
    for (int k = 0; k < 2048; ++k)
        acc += hrow[k] * wba[(long)k * 64 + n];
    const int hk4 = n >> 2, r = n & 3;
    if (r < 2) {
        bbuf[(long)m * 32 + hk4 * 2 + r] = 1.f / (1.f + expf(-acc));
    } else {
        const int hv = hk4 * 2 + (r - 2);
        float x = acc + dt_bias[hv];
        float sp = (x > 20.f) ? x : log1pf(expf(x));
        gbuf[(long)m * 32 + hv] = -expf(A_log[hv]) * sp;   // raw g (log of decay)
    }
}

// ---------- causal depthwise conv (K=4) + silu + per-head l2norm, bf16 out ----------
__global__ __launch_bounds__(256) void conv_kernel(const u16* __restrict__ qkvb,
                                                   const float* __restrict__ cw,
                                                   u16* __restrict__ qfb,
                                                   u16* __restrict__ kfb,
                                                   u16* __restrict__ vbuf)
{
    const int bid = blockIdx.x;          // bs*4 + part
    const int bs = bid >> 2, part = bid & 3;
    const int c = part * 2048 + threadIdx.x * 8;
    int n;
    if (c < 2048)       n = (c >> 7) * 512 + (c & 127);
    else if (c < 4096) { int c2 = c - 2048; n = (c2 >> 7) * 512 + 128 + (c2 & 127); }
    else               { int c2 = c - 4096; n = (c2 >> 8) * 512 + 256 + (c2 & 255); }
    const int s = bs & 2047;
    const long base = (long)bs * 8192 + n;

    float x0[8], x1[8], x2[8], x3[8];
#pragma unroll
    for (int i = 0; i < 8; ++i) { x0[i] = 0.f; x1[i] = 0.f; x2[i] = 0.f; }
    { uint4 r = *(const uint4*)&qkvb[base]; unpack8(r, x3); }
    if (s >= 1) { uint4 r = *(const uint4*)&qkvb[base - 8192];     unpack8(r, x2); }
    if (s >= 2) { uint4 r = *(const uint4*)&qkvb[base - 2 * 8192]; unpack8(r, x1); }
    if (s >= 3) { uint4 r = *(const uint4*)&qkvb[base - 3 * 8192]; unpack8(r, x0); }

    float v[8]; float ss = 0.f;
#pragma unroll
    for (int i = 0; i < 8; ++i) {
        float4 w = *(const float4*)&cw[(c + i) * 4];
        float a = x0[i] * w.x + x1[i] * w.y + x2[i] * w.z + x3[i] * w.w;
        v[i] = a / (1.f + expf(-a));
        ss += v[i] * v[i];
    }
    if (part < 2) {   // q/k: l2norm over 128-ch head
        ss = row16_allreduce(ss);
        float rn = rsqrtf(ss + 1e-6f);
#pragma unroll
        for (int i = 0; i < 8; ++i) v[i] *= rn;
        u16* dst = (part == 0 ? qfb : kfb) + (long)bs * 2048 + (c & 2047);
        uint4 o = make_uint4(pack2(v[0], v[1]), pack2(v[2], v[3]), pack2(v[4], v[5]), pack2(v[6], v[7]));
        *(uint4*)dst = o;
    } else {          // v: bf16 out
        uint4 o = make_uint4(pack2(v[0], v[1]), pack2(v[2], v[3]), pack2(v[4], v[5]), pack2(v[6], v[7]));
        *(uint4*)&vbuf[(long)bs * 4096 + (c - 4096)] = o;
    }
}

// ======================= chunked delta-rule scan (MFMA) =======================
// Per 32-step tile with state S_in and inclusive cum-log-decay G_t (Gamma_t=e^{G_t}):
//   (I+L) delta = R,  L_tj = beta_t e^{G_t-G_j} (k_t.k_j)  (j<t)
//   R_t = beta_t v_t - beta_t Gamma_t (k_t.S_in)
//   o_t = scale*Gamma_t*(q_t.S_in) + sum_{j<=t} scale e^{G_t-G_j} (q_t.k_j) delta_j
//   S_out = Gamma_31 S_in + sum_j e^{G31-G_j} k_j (x) delta_j
// T = (I+L)^{-1} and all coeffs depend only on K,g,beta -> parallel prep kernel.
// T stored as hi/lo bf16 pair (lo = T - bf16(T)); delta = Thi@R + Tlo@R.

#define KL_S 136   // u16 stride for Kl/Ql rows (pad vs 128 to spread banks)
#define KT_S 40    // u16 stride for K^T rows (32 + pad)
#define TL_S 40
#define GL_S 40
#define RT_S 40
#define SBT_S 136
#define SF_S 132
#define SCALE_QK 0.08838834764831845f

// ---------- prep: per (b,h,tile): T matrix (bf16 hi/lo) + coefficient arrays ----------
__global__ __launch_bounds__(64) void prep_kernel(const u16* __restrict__ kfb,
                                                  const float* __restrict__ gbuf,
                                                  const float* __restrict__ bbuf,
                                                  u16* __restrict__ Tbuf,
                                                  float* __restrict__ Cbuf)
{
    __shared__ __align__(16) u16 Kl[32 * KL_S];
    __shared__ __align__(16) float Lf[32 * 33];
    __shared__ __align__(16) float Tt[32 * 32];
    __shared__ float garr[32], barr[32], Gc[32];

    const int bid = blockIdx.x;                 // (b*32+h)*64 + tile
    const int b = bid >> 11, h = (bid >> 6) & 31, tile = bid & 63;
    const int hk = h >> 1;
    const int tid = threadIdx.x;
    const int lanelo = tid & 15, quad = tid >> 4;
    const long rowbase = (long)b * 2048 + tile * 32;

    // stage K tile (reg->LDS, padded rows)
    {
        const int row = tid >> 1, half = tid & 1;
        const u16* src = &kfb[(rowbase + row) * 2048 + hk * 128 + half * 64];
#pragma unroll
        for (int i = 0; i < 8; ++i) {
            uint4 v = *(const uint4*)(src + i * 8);
            *(uint4*)&Kl[row * KL_S + half * 64 + i * 8] = v;
        }
    }
    if (tid < 32) {
        garr[tid] = gbuf[(rowbase + tid) * 32 + h];
        barr[tid] = bbuf[(rowbase + tid) * 32 + h];
    }
    __syncthreads();
    if (tid == 0) {
        float a = 0.f;
        for (int t = 0; t < 32; ++t) { a += garr[t]; Gc[t] = a; }
    }
    __syncthreads();

    // CC = K @ K^T  (32x32x128)
    f32x4 cc[2][2];
#pragma unroll
    for (int mt = 0; mt < 2; ++mt)
#pragma unroll
        for (int nt = 0; nt < 2; ++nt) cc[mt][nt] = (f32x4)0.f;
#pragma unroll
    for (int kt = 0; kt < 4; ++kt) {
        bf16x8 a0 = *(const bf16x8*)&Kl[(0 * 16 + lanelo) * KL_S + kt * 32 + quad * 8];
        bf16x8 a1 = *(const bf16x8*)&Kl[(1 * 16 + lanelo) * KL_S + kt * 32 + quad * 8];
        cc[0][0] = __builtin_amdgcn_mfma_f32_16x16x32_bf16(a0, a0, cc[0][0], 0, 0, 0);
        cc[0][1] = __builtin_amdgcn_mfma_f32_16x16x32_bf16(a0, a1, cc[0][1], 0, 0, 0);
        cc[1][0] = __builtin_amdgcn_mfma_f32_16x16x32_bf16(a1, a0, cc[1][0], 0, 0, 0);
        cc[1][1] = __builtin_amdgcn_mfma_f32_16x16x32_bf16(a1, a1, cc[1][1], 0, 0, 0);
    }
    // L matrix
#pragma unroll
    for (int mt = 0; mt < 2; ++mt)
#pragma unroll
        for (int nt = 0; nt < 2; ++nt)
#pragma unroll
            for (int r = 0; r < 4; ++r) {
                const int t = mt * 16 + quad * 4 + r, j = nt * 16 + lanelo;
                float L = (j < t) ? barr[t] * __expf(Gc[t] - Gc[j]) * cc[mt][nt][r] : 0.f;
                Lf[t * 33 + j] = L;
            }
    __syncthreads();

    // forward substitution: T = (I+L)^{-1}, column per lane (lanes 0..31)
    if (tid < 32) {
        const int c = tid;
        float T[32];
#pragma unroll
        for (int t = 0; t < 32; ++t) {
            float s = (t == c) ? 1.f : 0.f;
#pragma unroll
            for (int j = 0; j < t; ++j) s -= Lf[t * 33 + j] * T[j];
            T[t] = s;
        }
#pragma unroll
        for (int t = 0; t < 32; ++t) Tt[t * 32 + c] = T[t];
    }
    // coeffs
    if (tid < 32) {
        const float G31 = Gc[31];
        const float eg = __expf(Gc[tid]);
        float* cb = &Cbuf[(long)bid * 256];
        cb[tid]       = barr[tid];              // beta
        cb[32 + tid]  = barr[tid] * eg;         // beta*Gamma
        cb[64 + tid]  = SCALE_QK * eg;          // scale*Gamma
        cb[96 + tid]  = __expf(G31 - Gc[tid]);  // e^{G31-Gt}
        cb[128 + tid] = Gc[tid];                // Gt
        if (tid == 0) cb[192] = __expf(G31);    // Gamma_C
    }
    __syncthreads();
    // pack T -> bf16 hi/lo global, row-major [t][c]; hi rows 0..31, lo rows 32..63
    {
        const float* tp = &Tt[tid * 16];
        u32 hi[8], lo[8];
#pragma unroll
        for (int i = 0; i < 8; ++i) {
            u16 h0 = f2bf(tp[2 * i]),     h1 = f2bf(tp[2 * i + 1]);
            float l0 = tp[2 * i] - bf2f(h0), l1 = tp[2 * i + 1] - bf2f(h1);
            hi[i] = (u32)h0 | ((u32)h1 << 16);
            lo[i] = pack2(l0, l1);
        }
        u16* dst = &Tbuf[(long)bid * 2048 + tid * 16];
        *(uint4*)dst       = make_uint4(hi[0], hi[1], hi[2], hi[3]);
        *(uint4*)(dst + 8) = make_uint4(hi[4], hi[5], hi[6], hi[7]);
        u16* dstl = dst + 1024;
        *(uint4*)dstl       = make_uint4(lo[0], lo[1], lo[2], lo[3]);
        *(uint4*)(dstl + 8) = make_uint4(lo[4], lo[5], lo[6], lo[7]);
    }
}

// ---------- main scan: all-MFMA tiles ----------
__global__ __launch_bounds__(256) void scan_kernel(const u16* __restrict__ kfb,
                                                   const u16* __restrict__ qfb,
                                                   const u16* __restrict__ vbuf,
                                                   const u16* __restrict__ Tbuf,
                                                   const float* __restrict__ Cbuf,
                                                   u16* __restrict__ obuf)
{
    __shared__ __align__(16) u16 Kl[32 * KL_S];
    __shared__ __align__(16) u16 Ql[32 * KL_S];
    __shared__ __align__(16) u16 KTl[128 * KT_S];
    __shared__ __align__(16) u16 Tl[64 * TL_S];     // rows 0..31 hi, 32..63 lo
    __shared__ __align__(16) u16 Gl[32 * GL_S];
    __shared__ __align__(16) u16 RTl[16 * RT_S];
    __shared__ __align__(16) u16 DTl[16 * RT_S];
    __shared__ __align__(16) u16 DTs[16 * RT_S];
    __shared__ __align__(16) u16 Sbt[16 * SBT_S];
    __shared__ __align__(16) float Sf[16 * SF_S];
    __shared__ __align__(16) u16 Vl[32 * 16];
    __shared__ __align__(16) float Cf[256];

    const int bid = blockIdx.x;      // (b, h, colblock)
    const int b = bid >> 8;
    const int h = (bid >> 3) & 31;
    const int c0 = (bid & 7) * 16;
    const int hk = h >> 1;
    const int tid = threadIdx.x;
    const int lane = tid & 63;
    const int w = tid >> 6;
    const int lanelo = lane & 15;
    const int quad = lane >> 4;
    const long rowbase = (long)b * 2048;
    const long tIdxBase = ((long)(b * 32 + h)) * 64;

    for (int i = tid; i < 16 * SF_S; i += 256) Sf[i] = 0.f;
    for (int i = tid; i < 16 * SBT_S; i += 256) Sbt[i] = 0;
    __syncthreads();

    const int srow = tid >> 3, scp = tid & 7;
    const u16* kg = &kfb[(rowbase + srow) * 2048 + hk * 128 + scp * 16];
    const u16* qg = &qfb[(rowbase + srow) * 2048 + hk * 128 + scp * 16];
    const int mtQK = w >> 1, ntQK = w & 1;
    const int mtY = w & 1;
    const bool isY = (w < 2);

    for (int tile = 0; tile < 64; ++tile) {
        const int t0 = tile * 32;
        // ---- PH0: stage (reg->padded LDS for K/Q/T; async for V/Cf)
        uint4 k0 = *(const uint4*)(kg + (long)t0 * 2048);
        uint4 k1 = *(const uint4*)(kg + (long)t0 * 2048 + 8);
        uint4 q0 = *(const uint4*)(qg + (long)t0 * 2048);
        uint4 q1 = *(const uint4*)(qg + (long)t0 * 2048 + 8);
        uint4 tt = *(const uint4*)&Tbuf[(tIdxBase + tile) * 2048 + tid * 8];
        if (w == 0) {
            const int r = tid >> 1, c8 = (tid & 1) * 8;
            async16(&vbuf[(rowbase + t0 + r) * 4096 + h * 128 + c0 + c8], &Vl[tid * 8]);
        } else if (w == 1) {
            const int u = tid - 64;
            async16(&Cbuf[(tIdxBase + tile) * 256 + u * 4], &Cf[u * 4]);
        }
        *(uint4*)&Kl[srow * KL_S + scp * 16] = k0;
        *(uint4*)&Kl[srow * KL_S + scp * 16 + 8] = k1;
        *(uint4*)&Ql[srow * KL_S + scp * 16] = q0;
        *(uint4*)&Ql[srow * KL_S + scp * 16 + 8] = q1;
        {   // K^T scatter (raw bf16)
            u32 ws_[8] = { k0.x, k0.y, k0.z, k0.w, k1.x, k1.y, k1.z, k1.w };
#pragma unroll
            for (int i = 0; i < 8; ++i) {
                KTl[(scp * 16 + 2 * i) * KT_S + srow] = (u16)(ws_[i] & 0xffffu);
                KTl[(scp * 16 + 2 * i + 1) * KT_S + srow] = (u16)(ws_[i] >> 16);
            }
        }
        {   // T hi/lo -> LDS (256 threads x 8 u16 = 2048)
            const int r = tid >> 2, c8 = (tid & 3) * 8;
            *(uint4*)&Tl[r * TL_S + c8] = tt;
        }
        __syncthreads();   // staging complete

        // ---- PH1: QK^T, Y|O1, R
        f32x4 qk = (f32x4)0.f;
#pragma unroll
        for (int kt = 0; kt < 4; ++kt) {
            bf16x8 aq = *(const bf16x8*)&Ql[(mtQK * 16 + lanelo) * KL_S + kt * 32 + quad * 8];
            bf16x8 bk = *(const bf16x8*)&Kl[(ntQK * 16 + lanelo) * KL_S + kt * 32 + quad * 8];
            qk = __builtin_amdgcn_mfma_f32_16x16x32_bf16(aq, bk, qk, 0, 0, 0);
        }
        const u16* aYsrc = isY ? Kl : Ql;
        f32x4 yo = (f32x4)0.f;
#pragma unroll
        for (int kt = 0; kt < 4; ++kt) {
            bf16x8 a = *(const bf16x8*)&aYsrc[(mtY * 16 + lanelo) * KL_S + kt * 32 + quad * 8];
            bf16x8 bs = *(const bf16x8*)&Sbt[lanelo * SBT_S + kt * 32 + quad * 8];
            yo = __builtin_amdgcn_mfma_f32_16x16x32_bf16(a, bs, yo, 0, 0, 0);
        }
        {   // G~ = scale * e^{Gt-Gj} * QK, masked j<=t
            f32x4 gt4 = *(const f32x4*)&Cf[128 + mtQK * 16 + quad * 4];
            float gj = Cf[128 + ntQK * 16 + lanelo];
#pragma unroll
            for (int r = 0; r < 4; ++r) {
                const int t = mtQK * 16 + quad * 4 + r, j = ntQK * 16 + lanelo;
                float gv = (j <= t) ? qk[r] * __expf(gt4[r] - gj) * SCALE_QK : 0.f;
                Gl[t * GL_S + j] = f2bf(gv);
            }
        }
        if (isY) {   // R_t = beta*v - beta*Gamma*Y ; write R^T
            f32x4 bt4 = *(const f32x4*)&Cf[0 + mtY * 16 + quad * 4];
            f32x4 bg4 = *(const f32x4*)&Cf[32 + mtY * 16 + quad * 4];
            float rv[4];
#pragma unroll
            for (int r = 0; r < 4; ++r) {
                float vv = bf2f(Vl[(mtY * 16 + quad * 4 + r) * 16 + lanelo]);
                rv[r] = bt4[r] * vv - bg4[r] * yo[r];
            }
            *(uint2*)&RTl[lanelo * RT_S + mtY * 16 + quad * 4] =
                make_uint2(pack2(rv[0], rv[1]), pack2(rv[2], rv[3]));
        }
        __syncthreads();   // B: RTl, Gl ready

        // ---- PH2: delta = Thi @ R + Tlo @ R
        if (isY) {
            bf16x8 ath = *(const bf16x8*)&Tl[(mtY * 16 + lanelo) * TL_S + quad * 8];
            bf16x8 atl = *(const bf16x8*)&Tl[(32 + mtY * 16 + lanelo) * TL_S + quad * 8];
            bf16x8 br  = *(const bf16x8*)&RTl[lanelo * RT_S + quad * 8];
            f32x4 dl = __builtin_amdgcn_mfma_f32_16x16x32_bf16(ath, br, (f32x4)0.f, 0, 0, 0);
            dl = __builtin_amdgcn_mfma_f32_16x16x32_bf16(atl, br, dl, 0, 0, 0);
            f32x4 ec4 = *(const f32x4*)&Cf[96 + mtY * 16 + quad * 4];
            *(uint2*)&DTl[lanelo * RT_S + mtY * 16 + quad * 4] =
                make_uint2(pack2(dl[0], dl[1]), pack2(dl[2], dl[3]));
            *(uint2*)&DTs[lanelo * RT_S + mtY * 16 + quad * 4] =
                make_uint2(pack2(dl[0] * ec4[0], dl[1] * ec4[1]),
                           pack2(dl[2] * ec4[2], dl[3] * ec4[3]));
        }
        __syncthreads();   // C: DTl/DTs ready

        // ---- PH3: O = so*O1 + G~@delta ; S = GammaC*S + K^T@(eC*delta)
        if (!isY) {
            const int mt = w - 2;
            bf16x8 ag = *(const bf16x8*)&Gl[(mt * 16 + lanelo) * GL_S + quad * 8];
            bf16x8 bd = *(const bf16x8*)&DTl[lanelo * RT_S + quad * 8];
            f32x4 oi = __builtin_amdgcn_mfma_f32_16x16x32_bf16(ag, bd, (f32x4)0.f, 0, 0, 0);
            f32x4 so4 = *(const f32x4*)&Cf[64 + mt * 16 + quad * 4];
#pragma unroll
            for (int r = 0; r < 4; ++r) {
                float ov = so4[r] * yo[r] + oi[r];
                obuf[((rowbase + t0 + mt * 16 + quad * 4 + r) * 32 + h) * 128 + c0 + lanelo] = f2bf(ov);
            }
        }
        const float gC = Cf[192];
#pragma unroll
        for (int s = 0; s < 2; ++s) {
            const int mt = w * 2 + s;
            bf16x8 ak = *(const bf16x8*)&KTl[(mt * 16 + lanelo) * KT_S + quad * 8];
            bf16x8 bd = *(const bf16x8*)&DTs[lanelo * RT_S + quad * 8];
            f32x4 ds4 = __builtin_amdgcn_mfma_f32_16x16x32_bf16(ak, bd, (f32x4)0.f, 0, 0, 0);
            float* sp = &Sf[lanelo * SF_S + mt * 16 + quad * 4];
            f32x4 sv = *(const f32x4*)sp;
#pragma unroll
            for (int r = 0; r < 4; ++r) sv[r] = gC * sv[r] + ds4[r];
            *(f32x4*)sp = sv;
            *(uint2*)&Sbt[lanelo * SBT_S + mt * 16 + quad * 4] =
                make_uint2(pack2(sv[0], sv[1]), pack2(sv[2], sv[3]));
        }
        __syncthreads();   // D: S ready for next tile
    }
}

// ---------- RMS-norm + gating ----------
__global__ __launch_bounds__(128) void gate_kernel(const u16* __restrict__ obuf,
                                                   const u16* __restrict__ zbuf,
                                                   const float* __restrict__ norm_w,
                                                   u16* __restrict__ ybuf)
{
    const int bid = blockIdx.x;          // bs*32 + hv
    const int bs = bid >> 5, hv = bid & 31;
    const int dv = threadIdx.x;
    __shared__ float red[2];
    float v = bf2f(obuf[(long)bid * 128 + dv]);
    float ss = v * v;
    ss += __shfl_xor(ss, 1);  ss += __shfl_xor(ss, 2);  ss += __shfl_xor(ss, 4);
    ss += __shfl_xor(ss, 8);  ss += __shfl_xor(ss, 16); ss += __shfl_xor(ss, 32);
    if ((dv & 63) == 0) red[dv >> 6] = ss;
    __syncthreads();
    const float mean = (red[0] + red[1]) * (1.f / 128.f);
    const float rstd = rsqrtf(mean + 1e-6f);
    const int hk = hv >> 1;
    const float z = bf2f(zbuf[(long)bs * 4096 + hk * 256 + (hv & 1) * 128 + dv]);
    const float y = v * rstd * norm_w[dv] * (z / (1.f + expf(-z)));
    ybuf[(long)bs * 4096 + hv * 128 + dv] = f2bf(y);
}

// ---------- launch ----------
extern "C" void kernel_launch(void* const* d_in, const int* in_sizes, int n_in,
                              void* d_out, int out_size, void* d_ws, size_t ws_size,
                              hipStream_t stream)
{
    const float* hs      = (const float*)d_in[0];
    const float* w_qkvz  = (const float*)d_in[1];
    const float* w_ba    = (const float*)d_in[2];
    const float* conv_w  = (const float*)d_in[3];
    const float* A_log   = (const float*)d_in[4];
    const float* dt_bias = (const float*)d_in[5];
    const float* norm_w  = (const float*)d_in[6];
    const float* w_out   = (const float*)d_in[7];

    char* ws = (char*)d_ws;
    u16*   qkvb  = (u16*)ws;                       //  [0, 67,108,864)
    u16*   kfb   = (u16*)(ws + 67108864);          //  16,777,216
    u16*   qfb   = (u16*)(ws + 83886080);          //  16,777,216
    u16*   vbuf  = (u16*)(ws + 100663296);         //  33,554,432
    u16*   Tbuf  = (u16*)(ws + 134217728);         //  16,777,216 (hi/lo)
    float* Cbuf  = (float*)(ws + 150994944);       //   4,194,304
    float* gbuf  = (float*)(ws + 155189248);       //     524,288
    float* bbuf  = (float*)(ws + 155713536);       //     524,288
    u16*   zbuf  = (u16*)(ws + 156237824);         //  33,554,432 (end 189,792,256)
    // lifetime-disjoint aliases:
    u16*   wqkvz_t = (u16*)(ws + 67108864);        // 50.3MB [kfb..vbuf-head], dead before conv
    u16*   hs_b    = (u16*)(ws + 117440512);       // 16.8MB [vbuf tail], dead before conv
    u16*   obuf    = (u16*)ws;                     // 33.6MB over dead qkvb-lo
    u16*   wout_t  = (u16*)(ws + 33554432);        // 16.8MB over dead qkvb-hi
    u16*   ybuf    = (u16*)(ws + 67108864);        // 33.6MB over kfb+qfb (dead after scan)

    // 1) dtype prep
    f2b_kernel<<<4096, 256, 0, stream>>>(hs, hs_b);
    transpose_f2b<<<dim3(384, 64), 256, 0, stream>>>(w_qkvz, wqkvz_t, 2048, 12288);
    // 2) qkvz projection, split store
    gemm_bt<2><<<dim3(96, 32), 256, 0, stream>>>(hs_b, wqkvz_t, qkvb, zbuf, 4096, 12288, 2048);
    // 3) raw g / beta
    ba_kernel<<<1024, 256, 0, stream>>>(hs, w_ba, A_log, dt_bias, gbuf, bbuf);
    // 4) conv + silu + l2norm (bf16 q/k/v)
    conv_kernel<<<4096 * 4, 256, 0, stream>>>(qkvb, conv_w, qfb, kfb, vbuf);
    // 5) prep: T matrices + coeffs (fully parallel over (b,h,tile))
    prep_kernel<<<4096, 64, 0, stream>>>(kfb, gbuf, bbuf, Tbuf, Cbuf);
    // 6) chunked MFMA scan
    scan_kernel<<<512, 256, 0, stream>>>(kfb, qfb, vbuf, Tbuf, Cbuf, obuf);
    // 7) w_out^T
    transpose_f2b<<<dim3(64, 128), 256, 0, stream>>>(w_out, wout_t, 4096, 2048);
    // 8) gating
    gate_kernel<<<4096 * 32, 128, 0, stream>>>(obuf, zbuf, norm_w, ybuf);
    // 9) out = y @ w_out
    gemm_bt<1><<<dim3(16, 32), 256, 0, stream>>>(ybuf, wout_t, d_out, nullptr, 4096, 2048, 4096);
}

// Round 6
// 1009.538 us; speedup vs baseline: 1.2814x; 1.0229x over previous
//
#include <hip/hip_runtime.h>

typedef unsigned short u16;
typedef unsigned int u32;

typedef __attribute__((ext_vector_type(8))) short bf16x8;
typedef __attribute__((ext_vector_type(4))) float f32x4;
typedef __attribute__((ext_vector_type(2))) float f32x2;

// ---------- helpers ----------
__device__ __forceinline__ float bf2f(u16 v) {
    union { u32 i; float f; } u; u.i = ((u32)v) << 16; return u.f;
}
__device__ __forceinline__ u16 f2bf(float f) {
    union { float f; u32 i; } u; u.f = f;
    u32 r = u.i + 0x7FFFu + ((u.i >> 16) & 1u);   // RNE
    return (u16)(r >> 16);
}
__device__ __forceinline__ u32 pack2(float lo, float hi) {
    return (u32)f2bf(lo) | ((u32)f2bf(hi) << 16);
}
__device__ __forceinline__ void unpack8(uint4 r, float* o) {
    o[0] = __uint_as_float(r.x << 16); o[1] = __uint_as_float(r.x & 0xffff0000u);
    o[2] = __uint_as_float(r.y << 16); o[3] = __uint_as_float(r.y & 0xffff0000u);
    o[4] = __uint_as_float(r.z << 16); o[5] = __uint_as_float(r.z & 0xffff0000u);
    o[6] = __uint_as_float(r.w << 16); o[7] = __uint_as_float(r.w & 0xffff0000u);
}
__device__ __forceinline__ void async16(const void* g, void* l) {
    __builtin_amdgcn_global_load_lds((const __attribute__((address_space(1))) void*)g,
                                     (__attribute__((address_space(3))) void*)l, 16, 0, 0);
}
// DPP butterfly adds (used by conv)
template<int CTRL>
__device__ __forceinline__ float dpp_add(float x) {
    int y = __builtin_amdgcn_update_dpp(0, __float_as_int(x), CTRL, 0xf, 0xf, true);
    return x + __int_as_float(y);
}
__device__ __forceinline__ float row16_allreduce(float x) {
    x = dpp_add<0xB1>(x);
    x = dpp_add<0x4E>(x);
    x = dpp_add<0x141>(x);
    x = dpp_add<0x140>(x);
    return x;
}

// ---------- fp32 -> bf16 convert ----------
__global__ __launch_bounds__(256) void f2b_kernel(const float* __restrict__ in,
                                                  u16* __restrict__ out)
{
    long i = ((long)blockIdx.x * 256 + threadIdx.x) * 8;
    float4 a = *(const float4*)&in[i], b = *(const float4*)&in[i + 4];
    uint4 o = make_uint4(pack2(a.x, a.y), pack2(a.z, a.w), pack2(b.x, b.y), pack2(b.z, b.w));
    *(uint4*)&out[i] = o;
}

// ---------- fp32 RxC -> bf16 CxR transpose ----------
__global__ __launch_bounds__(256) void transpose_f2b(const float* __restrict__ in,
                                                     u16* __restrict__ out, int R, int C)
{
    __shared__ float tile[32][33];
    const int r0 = blockIdx.y * 32, c0 = blockIdx.x * 32;
    const int tr = threadIdx.x >> 3;
    const int tc = (threadIdx.x & 7) * 4;
    float4 v = *(const float4*)&in[(long)(r0 + tr) * C + c0 + tc];
    tile[tr][tc] = v.x; tile[tr][tc + 1] = v.y; tile[tr][tc + 2] = v.z; tile[tr][tc + 3] = v.w;
    __syncthreads();
    uint2 o;
    o.x = pack2(tile[tc][tr], tile[tc + 1][tr]);
    o.y = pack2(tile[tc + 2][tr], tile[tc + 3][tr]);
    *(uint2*)&out[(long)(c0 + tr) * R + r0 + tc] = o;
}

// ---------- GEMM 128x128 (m97-style), kept for GEMM2 ----------
// CF=1: C fp32; CF=0: C bf16
template<int CF>
__global__ __launch_bounds__(256) void gemm_bt(const u16* __restrict__ A,
                                               const u16* __restrict__ Bt,
                                               void* __restrict__ Cp,
                                               void* __restrict__ Cp2,
                                               int M, int N, int K)
{
    __shared__ __align__(16) u16 As[128 * 32];
    __shared__ __align__(16) u16 Bs[128 * 32];

    const int tid = threadIdx.x;
    const int lane = tid & 63;
    const int wave = tid >> 6;
    const int wm = (wave >> 1) * 64;
    const int wn = (wave & 1) * 64;
    const int lanelo = lane & 15;
    const int quad = lane >> 4;
    const long m0 = (long)blockIdx.y * 128;
    const long n0 = (long)blockIdx.x * 128;

    f32x4 acc[4][4];
#pragma unroll
    for (int i = 0; i < 4; ++i)
#pragma unroll
        for (int j = 0; j < 4; ++j) acc[i][j] = (f32x4)0.0f;

    const u16* agp0 = A + (long)(m0 + wave * 16 + (lane >> 2)) * K + (lane & 3) * 8;
    const u16* agp1 = agp0 + 64 * (long)K;
    const u16* bgp0 = Bt + (long)(n0 + wave * 16 + (lane >> 2)) * K + (lane & 3) * 8;
    const u16* bgp1 = bgp0 + 64 * (long)K;
    u16* lA0 = &As[wave * 16 * 32];
    u16* lA1 = &As[(wave * 16 + 64) * 32];
    u16* lB0 = &Bs[wave * 16 * 32];
    u16* lB1 = &Bs[(wave * 16 + 64) * 32];

    for (int k0 = 0; k0 < K; k0 += 32) {
        __syncthreads();
        async16(agp0 + k0, lA0);
        async16(agp1 + k0, lA1);
        async16(bgp0 + k0, lB0);
        async16(bgp1 + k0, lB1);
        __syncthreads();

        bf16x8 af[4], bf[4];
#pragma unroll
        for (int mt = 0; mt < 4; ++mt)
            af[mt] = *(const bf16x8*)&As[(wm + mt * 16 + lanelo) * 32 + quad * 8];
#pragma unroll
        for (int nt = 0; nt < 4; ++nt)
            bf[nt] = *(const bf16x8*)&Bs[(wn + nt * 16 + lanelo) * 32 + quad * 8];
#pragma unroll
        for (int mt = 0; mt < 4; ++mt)
#pragma unroll
            for (int nt = 0; nt < 4; ++nt)
                acc[mt][nt] = __builtin_amdgcn_mfma_f32_16x16x32_bf16(af[mt], bf[nt], acc[mt][nt], 0, 0, 0);
    }

#pragma unroll
    for (int nt = 0; nt < 4; ++nt) {
        const long col = n0 + wn + nt * 16 + lanelo;
#pragma unroll
        for (int mt = 0; mt < 4; ++mt)
#pragma unroll
            for (int r = 0; r < 4; ++r) {
                long row = m0 + wm + mt * 16 + quad * 4 + r;
                if constexpr (CF == 1)      ((float*)Cp)[row * N + col] = acc[mt][nt][r];
                else                        ((u16*)Cp)[row * N + col] = f2bf(acc[mt][nt][r]);
            }
    }
}

// ---------- GEMM 256x256, BK=64, 8 waves, dbuf LDS, swizzled ----------
// split store: qkv cols -> Cp (compacted 8192-wide), z cols -> Cp2 (4096-wide)
// LDS layout: [256 rows][8 chunks of 16B], within-row chunk index XOR'ed with (row&7)
// (same involution on pre-swizzled global source and on ds_read -> conflict-free)
__global__ __launch_bounds__(512, 2) void gemm256_bt(const u16* __restrict__ A,
                                                     const u16* __restrict__ Bt,
                                                     void* __restrict__ Cp,
                                                     void* __restrict__ Cp2,
                                                     int M, int N, int K)
{
    __shared__ __align__(16) u16 As[2][256 * 64];
    __shared__ __align__(16) u16 Bs[2][256 * 64];

    const int tid = threadIdx.x;
    const int lane = tid & 63;
    const int w = tid >> 6;          // 0..7
    const int wm = w >> 2;           // 0..1  (M half)
    const int wn = w & 3;            // 0..3  (N quarter)
    const int lanelo = lane & 15;
    const int quad = lane >> 4;

    // bijective XCD swizzle (grid total divisible by 8: 48*16=768)
    const int nx = gridDim.x;
    const int nwg = nx * gridDim.y;
    const int orig = blockIdx.y * nx + blockIdx.x;
    const int cpx = nwg >> 3;
    const int swz = (orig & 7) * cpx + (orig >> 3);
    const long n0 = (long)(swz % nx) * 256;
    const long m0 = (long)(swz / nx) * 256;

    f32x4 acc[8][4];
#pragma unroll
    for (int i = 0; i < 8; ++i)
#pragma unroll
        for (int j = 0; j < 4; ++j) acc[i][j] = (f32x4)0.0f;

    const int kt_n = K >> 6;

    auto stage = [&](int buf, int kt) {
        const int k0 = kt << 6;
#pragma unroll
        for (int r = 0; r < 4; ++r) {
            const int c = r * 512 + tid;
            const int row = c >> 3, ci = c & 7;
            const int gcol = ((ci ^ (row & 7)) << 3);
            async16(&A[(m0 + row) * (long)K + k0 + gcol], &As[buf][c * 8]);
        }
#pragma unroll
        for (int r = 0; r < 4; ++r) {
            const int c = r * 512 + tid;
            const int row = c >> 3, ci = c & 7;
            const int gcol = ((ci ^ (row & 7)) << 3);
            async16(&Bt[(n0 + row) * (long)K + k0 + gcol], &Bs[buf][c * 8]);
        }
    };

    int buf = 0;
    stage(0, 0);
    __syncthreads();   // drain vmcnt before first compute

    for (int kt = 0; kt < kt_n; ++kt) {
        if (kt + 1 < kt_n) stage(buf ^ 1, kt + 1);   // prefetch next tile (other buffer)
#pragma unroll
        for (int kk = 0; kk < 2; ++kk) {
            bf16x8 a[8], b[4];
#pragma unroll
            for (int mf = 0; mf < 8; ++mf) {
                const int row = wm * 128 + mf * 16 + lanelo;
                const int ci = (kk * 4 + quad) ^ (row & 7);
                a[mf] = *(const bf16x8*)&As[buf][row * 64 + ci * 8];
            }
#pragma unroll
            for (int nf = 0; nf < 4; ++nf) {
                const int row = wn * 64 + nf * 16 + lanelo;
                const int ci = (kk * 4 + quad) ^ (row & 7);
                b[nf] = *(const bf16x8*)&Bs[buf][row * 64 + ci * 8];
            }
            __builtin_amdgcn_s_setprio(1);
#pragma unroll
            for (int mf = 0; mf < 8; ++mf)
#pragma unroll
                for (int nf = 0; nf < 4; ++nf)
                    acc[mf][nf] = __builtin_amdgcn_mfma_f32_16x16x32_bf16(a[mf], b[nf], acc[mf][nf], 0, 0, 0);
            __builtin_amdgcn_s_setprio(0);
        }
        __syncthreads();   // all waves' prefetch loads landed; buffers swap safely
        buf ^= 1;
    }

    // epilogue: split store qkv/z
#pragma unroll
    for (int nf = 0; nf < 4; ++nf) {
        const long col = n0 + wn * 64 + nf * 16 + lanelo;
        const int hkq = (int)col / 768;
        const int rr = (int)col - hkq * 768;
#pragma unroll
        for (int mf = 0; mf < 8; ++mf)
#pragma unroll
            for (int r = 0; r < 4; ++r) {
                const long row = m0 + wm * 128 + mf * 16 + quad * 4 + r;
                const u16 vv = f2bf(acc[mf][nf][r]);
                if (rr < 512) ((u16*)Cp )[row * 8192 + hkq * 512 + rr] = vv;
                else          ((u16*)Cp2)[row * 4096 + hkq * 256 + (rr - 512)] = vv;
            }
    }
}

// ---------- ba = hs @ w_ba: stores RAW g (log-decay) and beta ----------
__global__ __launch_bounds__(256) void ba_kernel(const float* __restrict__ hs,
                                                 const float* __restrict__ wba,
                                                 const float* __restrict__ A_log,
                                                 const float* __restrict__ dt_bias,
                                                 float* __restrict__ gbuf,
                                                 float* __restrict__ bbuf)
{
    const int m = blockIdx.x * 4 + (threadIdx.x >> 6);
    const int n = threadIdx.x & 63;
    const float* hrow = &hs[(long)m * 2048];
    float acc = 0.f;
#pragma unroll 8
    for (int k = 0; k < 2048; ++k)
        acc += hrow[k] * wba[(long)k * 64 + n];
    const int hk4 = n >> 2, r = n & 3;
    if (r < 2) {
        bbuf[(long)m * 32 + hk4 * 2 + r] = 1.f / (1.f + expf(-acc));
    } else {
        const int hv = hk4 * 2 + (r - 2);
        float x = acc + dt_bias[hv];
        float sp = (x > 20.f) ? x : log1pf(expf(x));
        gbuf[(long)m * 32 + hv] = -expf(A_log[hv]) * sp;   // raw g (log of decay)
    }
}

// ---------- causal depthwise conv (K=4) + silu + per-head l2norm, bf16 out ----------
__global__ __launch_bounds__(256) void conv_kernel(const u16* __restrict__ qkvb,
                                                   const float* __restrict__ cw,
                                                   u16* __restrict__ qfb,
                                                   u16* __restrict__ kfb,
                                                   u16* __restrict__ vbuf)
{
    const int bid = blockIdx.x;          // bs*4 + part
    const int bs = bid >> 2, part = bid & 3;
    const int c = part * 2048 + threadIdx.x * 8;
    int n;
    if (c < 2048)       n = (c >> 7) * 512 + (c & 127);
    else if (c < 4096) { int c2 = c - 2048; n = (c2 >> 7) * 512 + 128 + (c2 & 127); }
    else               { int c2 = c - 4096; n = (c2 >> 8) * 512 + 256 + (c2 & 255); }
    const int s = bs & 2047;
    const long base = (long)bs * 8192 + n;

    float x0[8], x1[8], x2[8], x3[8];
#pragma unroll
    for (int i = 0; i < 8; ++i) { x0[i] = 0.f; x1[i] = 0.f; x2[i] = 0.f; }
    { uint4 r = *(const uint4*)&qkvb[base]; unpack8(r, x3); }
    if (s >= 1) { uint4 r = *(const uint4*)&qkvb[base - 8192];     unpack8(r, x2); }
    if (s >= 2) { uint4 r = *(const uint4*)&qkvb[base - 2 * 8192]; unpack8(r, x1); }
    if (s >= 3) { uint4 r = *(const uint4*)&qkvb[base - 3 * 8192]; unpack8(r, x0); }

    float v[8]; float ss = 0.f;
#pragma unroll
    for (int i = 0; i < 8; ++i) {
        float4 w = *(const float4*)&cw[(c + i) * 4];
        float a = x0[i] * w.x + x1[i] * w.y + x2[i] * w.z + x3[i] * w.w;
        v[i] = a / (1.f + expf(-a));
        ss += v[i] * v[i];
    }
    if (part < 2) {   // q/k: l2norm over 128-ch head
        ss = row16_allreduce(ss);
        float rn = rsqrtf(ss + 1e-6f);
#pragma unroll
        for (int i = 0; i < 8; ++i) v[i] *= rn;
        u16* dst = (part == 0 ? qfb : kfb) + (long)bs * 2048 + (c & 2047);
        uint4 o = make_uint4(pack2(v[0], v[1]), pack2(v[2], v[3]), pack2(v[4], v[5]), pack2(v[6], v[7]));
        *(uint4*)dst = o;
    } else {          // v: bf16 out
        uint4 o = make_uint4(pack2(v[0], v[1]), pack2(v[2], v[3]), pack2(v[4], v[5]), pack2(v[6], v[7]));
        *(uint4*)&vbuf[(long)bs * 4096 + (c - 4096)] = o;
    }
}

// ======================= chunked delta-rule scan (MFMA) =======================
// Per 32-step tile with state S_in and inclusive cum-log-decay G_t (Gamma_t=e^{G_t}):
//   (I+L) delta = R,  L_tj = beta_t e^{G_t-G_j} (k_t.k_j)  (j<t)
//   R_t = beta_t v_t - beta_t Gamma_t (k_t.S_in)
//   o_t = scale*Gamma_t*(q_t.S_in) + sum_{j<=t} scale e^{G_t-G_j} (q_t.k_j) delta_j
//   S_out = Gamma_31 S_in + sum_j e^{G31-G_j} k_j (x) delta_j
// T = (I+L)^{-1} and all coeffs depend only on K,g,beta -> parallel prep kernel.
// T stored as hi/lo bf16 pair (lo = T - bf16(T)); delta = Thi@R + Tlo@R.

#define KL_S 136   // u16 stride for Kl/Ql rows (pad vs 128 to spread banks)
#define KT_S 40    // u16 stride for K^T rows (32 + pad)
#define TL_S 40
#define GL_S 40
#define RT_S 40
#define SBT_S 136
#define SF_S 132
#define SCALE_QK 0.08838834764831845f

// ---------- prep: per (b,h,tile): T matrix (bf16 hi/lo) + coefficient arrays ----------
__global__ __launch_bounds__(64) void prep_kernel(const u16* __restrict__ kfb,
                                                  const float* __restrict__ gbuf,
                                                  const float* __restrict__ bbuf,
                                                  u16* __restrict__ Tbuf,
                                                  float* __restrict__ Cbuf)
{
    __shared__ __align__(16) u16 Kl[32 * KL_S];
    __shared__ __align__(16) float Lf[32 * 33];
    __shared__ __align__(16) float Tt[32 * 32];
    __shared__ float garr[32], barr[32], Gc[32];

    const int bid = blockIdx.x;                 // (b*32+h)*64 + tile
    const int b = bid >> 11, h = (bid >> 6) & 31, tile = bid & 63;
    const int hk = h >> 1;
    const int tid = threadIdx.x;
    const int lanelo = tid & 15, quad = tid >> 4;
    const long rowbase = (long)b * 2048 + tile * 32;

    // stage K tile (reg->LDS, padded rows)
    {
        const int row = tid >> 1, half = tid & 1;
        const u16* src = &kfb[(rowbase + row) * 2048 + hk * 128 + half * 64];
#pragma unroll
        for (int i = 0; i < 8; ++i) {
            uint4 v = *(const uint4*)(src + i * 8);
            *(uint4*)&Kl[row * KL_S + half * 64 + i * 8] = v;
        }
    }
    if (tid < 32) {
        garr[tid] = gbuf[(rowbase + tid) * 32 + h];
        barr[tid] = bbuf[(rowbase + tid) * 32 + h];
    }
    __syncthreads();
    if (tid == 0) {
        float a = 0.f;
        for (int t = 0; t < 32; ++t) { a += garr[t]; Gc[t] = a; }
    }
    __syncthreads();

    // CC = K @ K^T  (32x32x128)
    f32x4 cc[2][2];
#pragma unroll
    for (int mt = 0; mt < 2; ++mt)
#pragma unroll
        for (int nt = 0; nt < 2; ++nt) cc[mt][nt] = (f32x4)0.f;
#pragma unroll
    for (int kt = 0; kt < 4; ++kt) {
        bf16x8 a0 = *(const bf16x8*)&Kl[(0 * 16 + lanelo) * KL_S + kt * 32 + quad * 8];
        bf16x8 a1 = *(const bf16x8*)&Kl[(1 * 16 + lanelo) * KL_S + kt * 32 + quad * 8];
        cc[0][0] = __builtin_amdgcn_mfma_f32_16x16x32_bf16(a0, a0, cc[0][0], 0, 0, 0);
        cc[0][1] = __builtin_amdgcn_mfma_f32_16x16x32_bf16(a0, a1, cc[0][1], 0, 0, 0);
        cc[1][0] = __builtin_amdgcn_mfma_f32_16x16x32_bf16(a1, a0, cc[1][0], 0, 0, 0);
        cc[1][1] = __builtin_amdgcn_mfma_f32_16x16x32_bf16(a1, a1, cc[1][1], 0, 0, 0);
    }
    // L matrix
#pragma unroll
    for (int mt = 0; mt < 2; ++mt)
#pragma unroll
        for (int nt = 0; nt < 2; ++nt)
#pragma unroll
            for (int r = 0; r < 4; ++r) {
                const int t = mt * 16 + quad * 4 + r, j = nt * 16 + lanelo;
                float L = (j < t) ? barr[t] * __expf(Gc[t] - Gc[j]) * cc[mt][nt][r] : 0.f;
                Lf[t * 33 + j] = L;
            }
    __syncthreads();

    // forward substitution: T = (I+L)^{-1}, column per lane (lanes 0..31)
    if (tid < 32) {
        const int c = tid;
        float T[32];
#pragma unroll
        for (int t = 0; t < 32; ++t) {
            float s = (t == c) ? 1.f : 0.f;
#pragma unroll
            for (int j = 0; j < t; ++j) s -= Lf[t * 33 + j] * T[j];
            T[t] = s;
        }
#pragma unroll
        for (int t = 0; t < 32; ++t) Tt[t * 32 + c] = T[t];
    }
    // coeffs
    if (tid < 32) {
        const float G31 = Gc[31];
        const float eg = __expf(Gc[tid]);
        float* cb = &Cbuf[(long)bid * 256];
        cb[tid]       = barr[tid];              // beta
        cb[32 + tid]  = barr[tid] * eg;         // beta*Gamma
        cb[64 + tid]  = SCALE_QK * eg;          // scale*Gamma
        cb[96 + tid]  = __expf(G31 - Gc[tid]);  // e^{G31-Gt}
        cb[128 + tid] = Gc[tid];                // Gt
        if (tid == 0) cb[192] = __expf(G31);    // Gamma_C
    }
    __syncthreads();
    // pack T -> bf16 hi/lo global, row-major [t][c]; hi rows 0..31, lo rows 32..63
    {
        const float* tp = &Tt[tid * 16];
        u32 hi[8], lo[8];
#pragma unroll
        for (int i = 0; i < 8; ++i) {
            u16 h0 = f2bf(tp[2 * i]),     h1 = f2bf(tp[2 * i + 1]);
            float l0 = tp[2 * i] - bf2f(h0), l1 = tp[2 * i + 1] - bf2f(h1);
            hi[i] = (u32)h0 | ((u32)h1 << 16);
            lo[i] = pack2(l0, l1);
        }
        u16* dst = &Tbuf[(long)bid * 2048 + tid * 16];
        *(uint4*)dst       = make_uint4(hi[0], hi[1], hi[2], hi[3]);
        *(uint4*)(dst + 8) = make_uint4(hi[4], hi[5], hi[6], hi[7]);
        u16* dstl = dst + 1024;
        *(uint4*)dstl       = make_uint4(lo[0], lo[1], lo[2], lo[3]);
        *(uint4*)(dstl + 8) = make_uint4(lo[4], lo[5], lo[6], lo[7]);
    }
}

// ---------- main scan: all-MFMA tiles ----------
__global__ __launch_bounds__(256) void scan_kernel(const u16* __restrict__ kfb,
                                                   const u16* __restrict__ qfb,
                                                   const u16* __restrict__ vbuf,
                                                   const u16* __restrict__ Tbuf,
                                                   const float* __restrict__ Cbuf,
                                                   u16* __restrict__ obuf)
{
    __shared__ __align__(16) u16 Kl[32 * KL_S];
    __shared__ __align__(16) u16 Ql[32 * KL_S];
    __shared__ __align__(16) u16 KTl[128 * KT_S];
    __shared__ __align__(16) u16 Tl[64 * TL_S];     // rows 0..31 hi, 32..63 lo
    __shared__ __align__(16) u16 Gl[32 * GL_S];
    __shared__ __align__(16) u16 RTl[16 * RT_S];
    __shared__ __align__(16) u16 DTl[16 * RT_S];
    __shared__ __align__(16) u16 DTs[16 * RT_S];
    __shared__ __align__(16) u16 Sbt[16 * SBT_S];
    __shared__ __align__(16) float Sf[16 * SF_S];
    __shared__ __align__(16) u16 Vl[32 * 16];
    __shared__ __align__(16) float Cf[256];

    const int bid = blockIdx.x;      // (b, h, colblock)
    const int b = bid >> 8;
    const int h = (bid >> 3) & 31;
    const int c0 = (bid & 7) * 16;
    const int hk = h >> 1;
    const int tid = threadIdx.x;
    const int lane = tid & 63;
    const int w = tid >> 6;
    const int lanelo = lane & 15;
    const int quad = lane >> 4;
    const long rowbase = (long)b * 2048;
    const long tIdxBase = ((long)(b * 32 + h)) * 64;

    for (int i = tid; i < 16 * SF_S; i += 256) Sf[i] = 0.f;
    for (int i = tid; i < 16 * SBT_S; i += 256) Sbt[i] = 0;
    __syncthreads();

    const int srow = tid >> 3, scp = tid & 7;
    const u16* kg = &kfb[(rowbase + srow) * 2048 + hk * 128 + scp * 16];
    const u16* qg = &qfb[(rowbase + srow) * 2048 + hk * 128 + scp * 16];
    const int mtQK = w >> 1, ntQK = w & 1;
    const int mtY = w & 1;
    const bool isY = (w < 2);

    for (int tile = 0; tile < 64; ++tile) {
        const int t0 = tile * 32;
        // ---- PH0: stage (reg->padded LDS for K/Q/T; async for V/Cf)
        uint4 k0 = *(const uint4*)(kg + (long)t0 * 2048);
        uint4 k1 = *(const uint4*)(kg + (long)t0 * 2048 + 8);
        uint4 q0 = *(const uint4*)(qg + (long)t0 * 2048);
        uint4 q1 = *(const uint4*)(qg + (long)t0 * 2048 + 8);
        uint4 tt = *(const uint4*)&Tbuf[(tIdxBase + tile) * 2048 + tid * 8];
        if (w == 0) {
            const int r = tid >> 1, c8 = (tid & 1) * 8;
            async16(&vbuf[(rowbase + t0 + r) * 4096 + h * 128 + c0 + c8], &Vl[tid * 8]);
        } else if (w == 1) {
            const int u = tid - 64;
            async16(&Cbuf[(tIdxBase + tile) * 256 + u * 4], &Cf[u * 4]);
        }
        *(uint4*)&Kl[srow * KL_S + scp * 16] = k0;
        *(uint4*)&Kl[srow * KL_S + scp * 16 + 8] = k1;
        *(uint4*)&Ql[srow * KL_S + scp * 16] = q0;
        *(uint4*)&Ql[srow * KL_S + scp * 16 + 8] = q1;
        {   // K^T scatter (raw bf16)
            u32 ws_[8] = { k0.x, k0.y, k0.z, k0.w, k1.x, k1.y, k1.z, k1.w };
#pragma unroll
            for (int i = 0; i < 8; ++i) {
                KTl[(scp * 16 + 2 * i) * KT_S + srow] = (u16)(ws_[i] & 0xffffu);
                KTl[(scp * 16 + 2 * i + 1) * KT_S + srow] = (u16)(ws_[i] >> 16);
            }
        }
        {   // T hi/lo -> LDS (256 threads x 8 u16 = 2048)
            const int r = tid >> 2, c8 = (tid & 3) * 8;
            *(uint4*)&Tl[r * TL_S + c8] = tt;
        }
        __syncthreads();   // staging complete

        // ---- PH1: QK^T, Y|O1, R
        f32x4 qk = (f32x4)0.f;
#pragma unroll
        for (int kt = 0; kt < 4; ++kt) {
            bf16x8 aq = *(const bf16x8*)&Ql[(mtQK * 16 + lanelo) * KL_S + kt * 32 + quad * 8];
            bf16x8 bk = *(const bf16x8*)&Kl[(ntQK * 16 + lanelo) * KL_S + kt * 32 + quad * 8];
            qk = __builtin_amdgcn_mfma_f32_16x16x32_bf16(aq, bk, qk, 0, 0, 0);
        }
        const u16* aYsrc = isY ? Kl : Ql;
        f32x4 yo = (f32x4)0.f;
#pragma unroll
        for (int kt = 0; kt < 4; ++kt) {
            bf16x8 a = *(const bf16x8*)&aYsrc[(mtY * 16 + lanelo) * KL_S + kt * 32 + quad * 8];
            bf16x8 bs = *(const bf16x8*)&Sbt[lanelo * SBT_S + kt * 32 + quad * 8];
            yo = __builtin_amdgcn_mfma_f32_16x16x32_bf16(a, bs, yo, 0, 0, 0);
        }
        {   // G~ = scale * e^{Gt-Gj} * QK, masked j<=t
            f32x4 gt4 = *(const f32x4*)&Cf[128 + mtQK * 16 + quad * 4];
            float gj = Cf[128 + ntQK * 16 + lanelo];
#pragma unroll
            for (int r = 0; r < 4; ++r) {
                const int t = mtQK * 16 + quad * 4 + r, j = ntQK * 16 + lanelo;
                float gv = (j <= t) ? qk[r] * __expf(gt4[r] - gj) * SCALE_QK : 0.f;
                Gl[t * GL_S + j] = f2bf(gv);
            }
        }
        if (isY) {   // R_t = beta*v - beta*Gamma*Y ; write R^T
            f32x4 bt4 = *(const f32x4*)&Cf[0 + mtY * 16 + quad * 4];
            f32x4 bg4 = *(const f32x4*)&Cf[32 + mtY * 16 + quad * 4];
            float rv[4];
#pragma unroll
            for (int r = 0; r < 4; ++r) {
                float vv = bf2f(Vl[(mtY * 16 + quad * 4 + r) * 16 + lanelo]);
                rv[r] = bt4[r] * vv - bg4[r] * yo[r];
            }
            *(uint2*)&RTl[lanelo * RT_S + mtY * 16 + quad * 4] =
                make_uint2(pack2(rv[0], rv[1]), pack2(rv[2], rv[3]));
        }
        __syncthreads();   // B: RTl, Gl ready

        // ---- PH2: delta = Thi @ R + Tlo @ R
        if (isY) {
            bf16x8 ath = *(const bf16x8*)&Tl[(mtY * 16 + lanelo) * TL_S + quad * 8];
            bf16x8 atl = *(const bf16x8*)&Tl[(32 + mtY * 16 + lanelo) * TL_S + quad * 8];
            bf16x8 br  = *(const bf16x8*)&RTl[lanelo * RT_S + quad * 8];
            f32x4 dl = __builtin_amdgcn_mfma_f32_16x16x32_bf16(ath, br, (f32x4)0.f, 0, 0, 0);
            dl = __builtin_amdgcn_mfma_f32_16x16x32_bf16(atl, br, dl, 0, 0, 0);
            f32x4 ec4 = *(const f32x4*)&Cf[96 + mtY * 16 + quad * 4];
            *(uint2*)&DTl[lanelo * RT_S + mtY * 16 + quad * 4] =
                make_uint2(pack2(dl[0], dl[1]), pack2(dl[2], dl[3]));
            *(uint2*)&DTs[lanelo * RT_S + mtY * 16 + quad * 4] =
                make_uint2(pack2(dl[0] * ec4[0], dl[1] * ec4[1]),
                           pack2(dl[2] * ec4[2], dl[3] * ec4[3]));
        }
        __syncthreads();   // C: DTl/DTs ready

        // ---- PH3: O = so*O1 + G~@delta ; S = GammaC*S + K^T@(eC*delta)
        if (!isY) {
            const int mt = w - 2;
            bf16x8 ag = *(const bf16x8*)&Gl[(mt * 16 + lanelo) * GL_S + quad * 8];
            bf16x8 bd = *(const bf16x8*)&DTl[lanelo * RT_S + quad * 8];
            f32x4 oi = __builtin_amdgcn_mfma_f32_16x16x32_bf16(ag, bd, (f32x4)0.f, 0, 0, 0);
            f32x4 so4 = *(const f32x4*)&Cf[64 + mt * 16 + quad * 4];
#pragma unroll
            for (int r = 0; r < 4; ++r) {
                float ov = so4[r] * yo[r] + oi[r];
                obuf[((rowbase + t0 + mt * 16 + quad * 4 + r) * 32 + h) * 128 + c0 + lanelo] = f2bf(ov);
            }
        }
        const float gC = Cf[192];
#pragma unroll
        for (int s = 0; s < 2; ++s) {
            const int mt = w * 2 + s;
            bf16x8 ak = *(const bf16x8*)&KTl[(mt * 16 + lanelo) * KT_S + quad * 8];
            bf16x8 bd = *(const bf16x8*)&DTs[lanelo * RT_S + quad * 8];
            f32x4 ds4 = __builtin_amdgcn_mfma_f32_16x16x32_bf16(ak, bd, (f32x4)0.f, 0, 0, 0);
            float* sp = &Sf[lanelo * SF_S + mt * 16 + quad * 4];
            f32x4 sv = *(const f32x4*)sp;
#pragma unroll
            for (int r = 0; r < 4; ++r) sv[r] = gC * sv[r] + ds4[r];
            *(f32x4*)sp = sv;
            *(uint2*)&Sbt[lanelo * SBT_S + mt * 16 + quad * 4] =
                make_uint2(pack2(sv[0], sv[1]), pack2(sv[2], sv[3]));
        }
        __syncthreads();   // D: S ready for next tile
    }
}

// ---------- RMS-norm + gating ----------
__global__ __launch_bounds__(128) void gate_kernel(const u16* __restrict__ obuf,
                                                   const u16* __restrict__ zbuf,
                                                   const float* __restrict__ norm_w,
                                                   u16* __restrict__ ybuf)
{
    const int bid = blockIdx.x;          // bs*32 + hv
    const int bs = bid >> 5, hv = bid & 31;
    const int dv = threadIdx.x;
    __shared__ float red[2];
    float v = bf2f(obuf[(long)bid * 128 + dv]);
    float ss = v * v;
    ss += __shfl_xor(ss, 1);  ss += __shfl_xor(ss, 2);  ss += __shfl_xor(ss, 4);
    ss += __shfl_xor(ss, 8);  ss += __shfl_xor(ss, 16); ss += __shfl_xor(ss, 32);
    if ((dv & 63) == 0) red[dv >> 6] = ss;
    __syncthreads();
    const float mean = (red[0] + red[1]) * (1.f / 128.f);
    const float rstd = rsqrtf(mean + 1e-6f);
    const int hk = hv >> 1;
    const float z = bf2f(zbuf[(long)bs * 4096 + hk * 256 + (hv & 1) * 128 + dv]);
    const float y = v * rstd * norm_w[dv] * (z / (1.f + expf(-z)));
    ybuf[(long)bs * 4096 + hv * 128 + dv] = f2bf(y);
}

// ---------- launch ----------
extern "C" void kernel_launch(void* const* d_in, const int* in_sizes, int n_in,
                              void* d_out, int out_size, void* d_ws, size_t ws_size,
                              hipStream_t stream)
{
    const float* hs      = (const float*)d_in[0];
    const float* w_qkvz  = (const float*)d_in[1];
    const float* w_ba    = (const float*)d_in[2];
    const float* conv_w  = (const float*)d_in[3];
    const float* A_log   = (const float*)d_in[4];
    const float* dt_bias = (const float*)d_in[5];
    const float* norm_w  = (const float*)d_in[6];
    const float* w_out   = (const float*)d_in[7];

    char* ws = (char*)d_ws;
    u16*   qkvb  = (u16*)ws;                       //  [0, 67,108,864)
    u16*   kfb   = (u16*)(ws + 67108864);          //  16,777,216
    u16*   qfb   = (u16*)(ws + 83886080);          //  16,777,216
    u16*   vbuf  = (u16*)(ws + 100663296);         //  33,554,432
    u16*   Tbuf  = (u16*)(ws + 134217728);         //  16,777,216 (hi/lo)
    float* Cbuf  = (float*)(ws + 150994944);       //   4,194,304
    float* gbuf  = (float*)(ws + 155189248);       //     524,288
    float* bbuf  = (float*)(ws + 155713536);       //     524,288
    u16*   zbuf  = (u16*)(ws + 156237824);         //  33,554,432 (end 189,792,256)
    // lifetime-disjoint aliases:
    u16*   wqkvz_t = (u16*)(ws + 67108864);        // 50.3MB [kfb..vbuf-head], dead before conv
    u16*   hs_b    = (u16*)(ws + 117440512);       // 16.8MB [vbuf tail], dead before conv
    u16*   obuf    = (u16*)ws;                     // 33.6MB over dead qkvb-lo
    u16*   wout_t  = (u16*)(ws + 33554432);        // 16.8MB over dead qkvb-hi
    u16*   ybuf    = (u16*)(ws + 67108864);        // 33.6MB over kfb+qfb (dead after scan)

    // 1) dtype prep
    f2b_kernel<<<4096, 256, 0, stream>>>(hs, hs_b);
    transpose_f2b<<<dim3(384, 64), 256, 0, stream>>>(w_qkvz, wqkvz_t, 2048, 12288);
    // 2) qkvz projection, 256x256 deep-pipelined GEMM, split store
    gemm256_bt<<<dim3(48, 16), 512, 0, stream>>>(hs_b, wqkvz_t, qkvb, zbuf, 4096, 12288, 2048);
    // 3) raw g / beta
    ba_kernel<<<1024, 256, 0, stream>>>(hs, w_ba, A_log, dt_bias, gbuf, bbuf);
    // 4) conv + silu + l2norm (bf16 q/k/v)
    conv_kernel<<<4096 * 4, 256, 0, stream>>>(qkvb, conv_w, qfb, kfb, vbuf);
    // 5) prep: T matrices + coeffs (fully parallel over (b,h,tile))
    prep_kernel<<<4096, 64, 0, stream>>>(kfb, gbuf, bbuf, Tbuf, Cbuf);
    // 6) chunked MFMA scan
    scan_kernel<<<512, 256, 0, stream>>>(kfb, qfb, vbuf, Tbuf, Cbuf, obuf);
    // 7) w_out^T
    transpose_f2b<<<dim3(64, 128), 256, 0, stream>>>(w_out, wout_t, 4096, 2048);
    // 8) gating
    gate_kernel<<<4096 * 32, 128, 0, stream>>>(obuf, zbuf, norm_w, ybuf);
    // 9) out = y @ w_out (128^2 kernel: 256^2 grid would be only 128 blocks)
    gemm_bt<1><<<dim3(16, 32), 256, 0, stream>>>(ybuf, wout_t, d_out, nullptr, 4096, 2048, 4096);
}